// Round 1
// baseline (219.937 us; speedup 1.0000x reference)
//
#include <hip/hip_runtime.h>

// Problem constants (from reference):
constexpr int kB  = 256;    // batch
constexpr int kN  = 1000;   // classes
constexpr int kA  = 32;     // attention parts
constexpr int kC  = 512;    // channels
constexpr int kAC = kA * kC;            // 16384 floats per (class or sample)
constexpr int kFeat  = kB * kAC;        // 4,194,304
constexpr int kCache = kN * kAC;        // 16,384,000

// ---------------------------------------------------------------------------
// Kernel 1: cls[b] = argmax_n labels[b,n]  (first-max semantics)
//           new_count[n] = count[n] + sum_b labels[b,n]
// Blocks [0,64): 4 waves/block, one 64-lane wave per sample b (argmax).
// Blocks [64,68): thread-per-class column sum (coalesced across n).
// ---------------------------------------------------------------------------
__global__ __launch_bounds__(256) void k_prep(
    const float* __restrict__ labels,
    const float* __restrict__ count,
    int*   __restrict__ cls,
    float* __restrict__ new_count)
{
    const int blk = blockIdx.x;
    if (blk < kB / 4) {
        const int wave = threadIdx.x >> 6;
        const int lane = threadIdx.x & 63;
        const int b = blk * 4 + wave;
        const float* row = labels + (size_t)b * kN;
        float best = -3.4e38f;
        int   bidx = kN;
        for (int n = lane; n < kN; n += 64) {
            float v = row[n];                 // coalesced across lanes
            if (v > best) { best = v; bidx = n; }  // ascending n => first max kept
        }
        #pragma unroll
        for (int off = 32; off >= 1; off >>= 1) {
            float ov = __shfl_xor(best, off, 64);
            int   oi = __shfl_xor(bidx, off, 64);
            if (ov > best || (ov == best && oi < bidx)) { best = ov; bidx = oi; }
        }
        if (lane == 0) cls[b] = bidx;
    } else {
        const int n = (blk - kB / 4) * 256 + threadIdx.x;
        if (n < kN) {
            float s = count[n];
            for (int b = 0; b < kB; ++b)      // coalesced across threads per b
                s += labels[(size_t)b * kN + n];
            new_count[n] = s;
        }
    }
}

// ---------------------------------------------------------------------------
// Kernel 2 (fused):
//  blocks [0, kN):            new_cache[n] = cache[n] + sum_{b: cls[b]==n} features[b]
//  blocks [kN, kN+kB*kA/2):   exch_features — per-(b,a) row select of anchor/features
// ---------------------------------------------------------------------------
__global__ __launch_bounds__(256) void k_main(
    const float* __restrict__ features,
    const float* __restrict__ anchor,
    const float* __restrict__ cache,
    const float* __restrict__ rand_u,
    const int*   __restrict__ cls,
    float* __restrict__ out_feat,
    float* __restrict__ out_cache)
{
    const int blk = blockIdx.x;
    if (blk < kN) {
        // -------- cache accumulate: one block per class --------
        __shared__ int scls[kB];
        for (int i = threadIdx.x; i < kB; i += 256) scls[i] = cls[i];
        __syncthreads();

        const int n = blk;
        const int t = threadIdx.x;                       // 256 threads
        const float4* src = (const float4*)(cache + (size_t)n * kAC);
        float4*       dst = (float4*)(out_cache + (size_t)n * kAC);

        // 16384 floats = 4096 float4 per class; 16 float4 per thread.
        float4 acc[16];
        #pragma unroll
        for (int i = 0; i < 16; ++i) acc[i] = src[t + i * 256];

        for (int b = 0; b < kB; ++b) {
            if (scls[b] == n) {                          // wave-uniform branch
                const float4* f = (const float4*)(features + (size_t)b * kAC);
                #pragma unroll
                for (int i = 0; i < 16; ++i) {
                    float4 v = f[t + i * 256];
                    acc[i].x += v.x; acc[i].y += v.y;
                    acc[i].z += v.z; acc[i].w += v.w;
                }
            }
        }
        #pragma unroll
        for (int i = 0; i < 16; ++i) dst[t + i * 256] = acc[i];
    } else {
        // -------- exchange: 2 rows of 512 floats per block --------
        const int rblk = blk - kN;                       // 0..4095
        const int row  = rblk * 2 + (threadIdx.x >> 7);  // flat (b*kA + a)
        const int c4   = threadIdx.x & 127;              // float4 index in row
        const int b    = row >> 5;
        const int a    = row & 31;

        const float ru = rand_u[row];                    // wave-uniform (row uniform per wave)
        const float4* src = (ru > 0.5f)
            ? (const float4*)(anchor + ((size_t)cls[b] * kA + a) * kC)
            : (const float4*)(features + (size_t)row * kC);
        ((float4*)(out_feat + (size_t)row * kC))[c4] = src[c4];
    }
}

// ---------------------------------------------------------------------------
extern "C" void kernel_launch(void* const* d_in, const int* in_sizes, int n_in,
                              void* d_out, int out_size, void* d_ws, size_t ws_size,
                              hipStream_t stream) {
    const float* features = (const float*)d_in[0];   // (B,A,C)
    const float* labels   = (const float*)d_in[1];   // (B,N)
    const float* anchor   = (const float*)d_in[2];   // (N,A,C)
    const float* cache    = (const float*)d_in[3];   // (N,A,C)
    const float* count    = (const float*)d_in[4];   // (N,)
    const float* rand_u   = (const float*)d_in[5];   // (B,A)

    float* out_feat  = (float*)d_out;                // (B,A,C)
    float* out_cache = out_feat + kFeat;             // (N,A,C)
    float* out_count = out_cache + kCache;           // (N,)

    int* cls = (int*)d_ws;                           // 256 ints scratch

    k_prep<<<kB / 4 + (kN + 255) / 256, 256, 0, stream>>>(labels, count, cls, out_count);
    k_main<<<kN + (kB * kA) / 2, 256, 0, stream>>>(features, anchor, cache, rand_u, cls,
                                                   out_feat, out_cache);
}

// Round 2
// 204.195 us; speedup vs baseline: 1.0771x; 1.0771x over previous
//
#include <hip/hip_runtime.h>

// Problem constants (from reference):
constexpr int kB  = 256;    // batch
constexpr int kN  = 1000;   // classes
constexpr int kA  = 32;     // attention parts
constexpr int kC  = 512;    // channels
constexpr int kAC = kA * kC;            // 16384 floats per (class or sample)
constexpr int kFeat  = kB * kAC;        // 4,194,304
constexpr int kCache = kN * kAC;        // 16,384,000

// ---------------------------------------------------------------------------
// Kernel 1: cls[b] = argmax_n labels[b,n]  (first-max semantics)
// 64 blocks x 256 threads; one 64-lane wave per sample b. Coalesced row read.
// ---------------------------------------------------------------------------
__global__ __launch_bounds__(256) void k_prep(
    const float* __restrict__ labels,
    int*   __restrict__ cls)
{
    const int wave = threadIdx.x >> 6;
    const int lane = threadIdx.x & 63;
    const int b = blockIdx.x * 4 + wave;
    const float* row = labels + (size_t)b * kN;
    float best = -3.4e38f;
    int   bidx = kN;
    for (int n = lane; n < kN; n += 64) {
        float v = row[n];                      // coalesced across lanes
        if (v > best) { best = v; bidx = n; }  // ascending n => first max kept
    }
    #pragma unroll
    for (int off = 32; off >= 1; off >>= 1) {
        float ov = __shfl_xor(best, off, 64);
        int   oi = __shfl_xor(bidx, off, 64);
        if (ov > best || (ov == best && oi < bidx)) { best = ov; bidx = oi; }
    }
    if (lane == 0) cls[b] = bidx;
}

// ---------------------------------------------------------------------------
// Kernel 2 (fused):
//  blocks [0, kN):   new_cache[n] = cache[n] + sum_{b: cls[b]==n} features[b]
//                    new_count[n] = count[n] + #matches      (ballot mask, no scan)
//  blocks [kN, ...): exch_features — per-(b,a) row select of anchor/features
// ---------------------------------------------------------------------------
__global__ __launch_bounds__(256) void k_main(
    const float* __restrict__ features,
    const float* __restrict__ anchor,
    const float* __restrict__ cache,
    const float* __restrict__ count,
    const float* __restrict__ rand_u,
    const int*   __restrict__ cls,
    float* __restrict__ out_feat,
    float* __restrict__ out_cache,
    float* __restrict__ out_count)
{
    const int blk = blockIdx.x;
    if (blk < kN) {
        // -------- cache accumulate: one block per class, ballot match list ----
        const int n = blk;
        const int t = threadIdx.x;                       // 256 threads = kB

        __shared__ unsigned long long masks[4];
        const int myc = cls[t];                          // coalesced 1KB read
        unsigned long long mb = __ballot(myc == n);
        if ((t & 63) == 0) masks[t >> 6] = mb;

        // issue the cache-row loads before the barrier (independent)
        const float4* src = (const float4*)(cache + (size_t)n * kAC);
        float4*       dst = (float4*)(out_cache + (size_t)n * kAC);
        float4 acc[16];
        #pragma unroll
        for (int i = 0; i < 16; ++i) acc[i] = src[t + i * 256];

        __syncthreads();

        int mtot = 0;
        #pragma unroll
        for (int w = 0; w < 4; ++w) {
            unsigned long long m = masks[w];
            mtot += __popcll(m);
            while (m) {                                  // usually 0 iterations
                const int bit = __ffsll((long long)m) - 1;
                m &= m - 1;
                const int b = w * 64 + bit;              // ascending b order
                const float4* f = (const float4*)(features + (size_t)b * kAC);
                #pragma unroll
                for (int i = 0; i < 16; ++i) {
                    float4 v = f[t + i * 256];
                    acc[i].x += v.x; acc[i].y += v.y;
                    acc[i].z += v.z; acc[i].w += v.w;
                }
            }
        }
        #pragma unroll
        for (int i = 0; i < 16; ++i) dst[t + i * 256] = acc[i];

        if (t == 0) out_count[n] = count[n] + (float)mtot;
    } else {
        // -------- exchange: 2 rows of 512 floats per block --------
        const int rblk = blk - kN;                       // 0..4095
        const int row  = rblk * 2 + (threadIdx.x >> 7);  // flat (b*kA + a)
        const int c4   = threadIdx.x & 127;              // float4 index in row
        const int b    = row >> 5;
        const int a    = row & 31;

        const float ru = rand_u[row];                    // wave-uniform per row
        const float4* src = (ru > 0.5f)
            ? (const float4*)(anchor + ((size_t)cls[b] * kA + a) * kC)
            : (const float4*)(features + (size_t)row * kC);
        ((float4*)(out_feat + (size_t)row * kC))[c4] = src[c4];
    }
}

// ---------------------------------------------------------------------------
extern "C" void kernel_launch(void* const* d_in, const int* in_sizes, int n_in,
                              void* d_out, int out_size, void* d_ws, size_t ws_size,
                              hipStream_t stream) {
    const float* features = (const float*)d_in[0];   // (B,A,C)
    const float* labels   = (const float*)d_in[1];   // (B,N)
    const float* anchor   = (const float*)d_in[2];   // (N,A,C)
    const float* cache    = (const float*)d_in[3];   // (N,A,C)
    const float* count    = (const float*)d_in[4];   // (N,)
    const float* rand_u   = (const float*)d_in[5];   // (B,A)

    float* out_feat  = (float*)d_out;                // (B,A,C)
    float* out_cache = out_feat + kFeat;             // (N,A,C)
    float* out_count = out_cache + kCache;           // (N,)

    int* cls = (int*)d_ws;                           // 256 ints scratch

    k_prep<<<kB / 4, 256, 0, stream>>>(labels, cls);
    k_main<<<kN + (kB * kA) / 2, 256, 0, stream>>>(features, anchor, cache, count,
                                                   rand_u, cls,
                                                   out_feat, out_cache, out_count);
}

// Round 6
// 196.932 us; speedup vs baseline: 1.1168x; 1.0369x over previous
//
#include <hip/hip_runtime.h>

// Native clang vector type — required by __builtin_nontemporal_{load,store}
// (HIP_vector_type float4 is rejected). Supports elementwise +=.
typedef float f32x4 __attribute__((ext_vector_type(4)));

// Problem constants (from reference):
constexpr int kB  = 256;    // batch
constexpr int kN  = 1000;   // classes
constexpr int kA  = 32;     // attention parts
constexpr int kC  = 512;    // channels
constexpr int kAC = kA * kC;            // 16384 floats per (class or sample)
constexpr int kFeat  = kB * kAC;        // 4,194,304
constexpr int kCache = kN * kAC;        // 16,384,000
constexpr int kRows  = kB * kA;         // 8192 (b,a) rows of 512 floats

constexpr int kCacheSplit = 2;                  // blocks per class row
constexpr int kCacheBlks  = kN * kCacheSplit;   // 2000
constexpr int kF4PerClass = kAC / 4;            // 4096 float4
constexpr int kF4PerHalf  = kF4PerClass / kCacheSplit;  // 2048
constexpr int kAccN       = kF4PerHalf / 256;   // 8 float4 per thread

constexpr int kExRowsPerBlk = 8;                // rows per exchange block
constexpr int kExBlks = kRows / kExRowsPerBlk;  // 1024
constexpr int kExIters = kExRowsPerBlk * 128 / 256;  // 4 float4 per thread

// ---------------------------------------------------------------------------
// Kernel 1: per-sample wave: cls[b] = argmax_n labels[b,n] (first-max), then
// lanes 0..31 compute the per-(b,a)-row source descriptor:
//   srcrow[row] = (rand_u[row] > 0.5) ? 0x80000000 | (cls*32 + a) : row
// so k_main's exchange path needs a single wave-uniform lookup.
// ---------------------------------------------------------------------------
__global__ __launch_bounds__(256) void k_prep(
    const float* __restrict__ labels,
    const float* __restrict__ rand_u,
    int* __restrict__ cls,
    int* __restrict__ srcrow)
{
    const int wave = threadIdx.x >> 6;
    const int lane = threadIdx.x & 63;
    const int b = blockIdx.x * 4 + wave;
    const float* row = labels + (size_t)b * kN;
    float best = -3.4e38f;
    int   bidx = kN;
    for (int n = lane; n < kN; n += 64) {
        float v = row[n];                      // coalesced across lanes
        if (v > best) { best = v; bidx = n; }  // ascending n => first max kept
    }
    #pragma unroll
    for (int off = 32; off >= 1; off >>= 1) {  // butterfly: all lanes converge
        float ov = __shfl_xor(best, off, 64);
        int   oi = __shfl_xor(bidx, off, 64);
        if (ov > best || (ov == best && oi < bidx)) { best = ov; bidx = oi; }
    }
    if (lane == 0) cls[b] = bidx;
    if (lane < kA) {
        const int r = b * kA + lane;
        const float ru = rand_u[r];
        srcrow[r] = (ru > 0.5f) ? (int)(0x80000000u | (unsigned)(bidx * kA + lane))
                                : r;
    }
}

// ---------------------------------------------------------------------------
// Kernel 2 (fused):
//  blocks [0, 2000):  new_cache (class n = blk/2, half = blk&1) + new_count
//  blocks [2000, 3024): exch_features — 8 rows/block, 4 float4/thread ILP
// ---------------------------------------------------------------------------
__global__ __launch_bounds__(256) void k_main(
    const float* __restrict__ features,
    const float* __restrict__ anchor,
    const float* __restrict__ cache,
    const float* __restrict__ count,
    const int*   __restrict__ cls,
    const int*   __restrict__ srcrow,
    float* __restrict__ out_feat,
    float* __restrict__ out_cache,
    float* __restrict__ out_count)
{
    const int blk = blockIdx.x;
    const int t = threadIdx.x;
    if (blk < kCacheBlks) {
        // -------- cache accumulate: 2 blocks per class, ballot match list ----
        const int n    = blk >> 1;
        const int half = blk & 1;

        __shared__ unsigned long long masks[4];
        const int myc = cls[t];                          // coalesced 1KB read
        unsigned long long mb = __ballot(myc == n);
        if ((t & 63) == 0) masks[t >> 6] = mb;

        const size_t base = (size_t)n * kF4PerClass + (size_t)half * kF4PerHalf;
        const f32x4* src = (const f32x4*)cache + base;
        f32x4*       dst = (f32x4*)out_cache + base;
        f32x4 acc[kAccN];
        #pragma unroll
        for (int i = 0; i < kAccN; ++i)
            acc[i] = __builtin_nontemporal_load(&src[t + i * 256]);  // read-once stream

        __syncthreads();

        int mtot = 0;
        #pragma unroll
        for (int w = 0; w < 4; ++w) {
            unsigned long long m = masks[w];
            mtot += __popcll(m);
            while (m) {                                  // usually 0 iterations
                const int bit = __ffsll((long long)m) - 1;
                m &= m - 1;
                const int b = w * 64 + bit;              // ascending b order
                const f32x4* f = (const f32x4*)features
                                + (size_t)b * kF4PerClass + (size_t)half * kF4PerHalf;
                #pragma unroll
                for (int i = 0; i < kAccN; ++i)
                    acc[i] += f[t + i * 256];
            }
        }
        #pragma unroll
        for (int i = 0; i < kAccN; ++i)
            __builtin_nontemporal_store(acc[i], &dst[t + i * 256]);

        if (t == 0 && half == 0) out_count[n] = count[n] + (float)mtot;
    } else {
        // -------- exchange: 8 rows of 512 floats per block, ILP 4 --------
        const int rblk = blk - kCacheBlks;               // 0..1023
        const int j0   = rblk * (kExRowsPerBlk * 128);   // base float4 index
        const f32x4* features4 = (const f32x4*)features;
        const f32x4* anchor4   = (const f32x4*)anchor;
        f32x4*       out4      = (f32x4*)out_feat;
        #pragma unroll
        for (int k = 0; k < kExIters; ++k) {
            const int j   = j0 + k * 256 + t;            // global float4 index
            const int row = j >> 7;                      // wave-uniform
            const int c4  = j & 127;
            const int s   = srcrow[row];                 // one uniform lookup
            const f32x4* srcb = (s >= 0) ? features4 : anchor4;
            const int r = s & 0x7fffffff;
            f32x4 v = srcb[(size_t)r * 128 + c4];
            __builtin_nontemporal_store(v, &out4[j]);
        }
    }
}

// ---------------------------------------------------------------------------
extern "C" void kernel_launch(void* const* d_in, const int* in_sizes, int n_in,
                              void* d_out, int out_size, void* d_ws, size_t ws_size,
                              hipStream_t stream) {
    const float* features = (const float*)d_in[0];   // (B,A,C)
    const float* labels   = (const float*)d_in[1];   // (B,N)
    const float* anchor   = (const float*)d_in[2];   // (N,A,C)
    const float* cache    = (const float*)d_in[3];   // (N,A,C)
    const float* count    = (const float*)d_in[4];   // (N,)
    const float* rand_u   = (const float*)d_in[5];   // (B,A)

    float* out_feat  = (float*)d_out;                // (B,A,C)
    float* out_cache = out_feat + kFeat;             // (N,A,C)
    float* out_count = out_cache + kCache;           // (N,)

    int* cls    = (int*)d_ws;                        // 256 ints
    int* srcrow = cls + kB;                          // 8192 ints

    k_prep<<<kB / 4, 256, 0, stream>>>(labels, rand_u, cls, srcrow);
    k_main<<<kCacheBlks + kExBlks, 256, 0, stream>>>(features, anchor, cache, count,
                                                     cls, srcrow,
                                                     out_feat, out_cache, out_count);
}